// Round 3
// baseline (85.394 us; speedup 1.0000x reference)
//
#include <hip/hip_runtime.h>
#include <math.h>

// ---- problem constants ----
#define NCH   2048
#define SZ    14
#define NPOS  (SZ*SZ)        // 196
#define NQ    (NPOS/4)       // 49 float4 per channel plane
#define NSL   64             // channel slices
#define CPS   (NCH/NSL)      // 32 channels per slice
#define BPB   16             // blocks per batch (NSL/4 waves-per-block)
#define NWIN  917
#define NB    64
#define PN    7
#define KPER  6              // ceil(361/64) strided candidates per lane
#define PART_BYTES (NB*NSL*NPOS*4)   // 3,211,264

// window tables (13 ratios)
__device__ const int g_rh[13]    = {4,3,5,6,5,7,8,6,10,7,9,7,10};
__device__ const int g_rw[13]    = {4,5,3,6,7,5,8,10,6,9,7,10,7};
__device__ const int g_wbase[14] = {0,121,241,361,442,522,602,651,696,741,789,837,877,917};

__device__ __forceinline__ void decode_box(int w, float& x1, float& y1,
                                           float& x2, float& y2, float& ar) {
  int r = 0;
  while (w >= g_wbase[r + 1]) ++r;
  const int l  = w - g_wbase[r];
  const int RH = g_rh[r], RW = g_rw[r];
  const int ww = SZ - RW + 1;
  const int xi = l / ww, yi = l % ww;
  const float fx1 = (float)(xi * 32 - 1);
  const float fy1 = (float)(yi * 32 - 1);
  x2 = fx1 + (float)(RH * 32);
  y2 = fy1 + (float)(RW * 32);
  x1 = fx1 < 0.f ? 0.f : fx1;
  y1 = fy1 < 0.f ? 0.f : fy1;
  ar = (x2 - x1 + 1.f) * (y2 - y1 + 1.f);
}

// fused: stream channel-sums; last block per batch does windows + NMS
__global__ __launch_bounds__(256) void k_fused(const float4* __restrict__ x,
                                               float4* __restrict__ part,
                                               int* __restrict__ cnt,
                                               float* __restrict__ out) {
  const int b    = blockIdx.x;
  const int tid  = threadIdx.x;
  const int lane = tid & 63;
  const int wave = tid >> 6;

  __shared__ float s[NPOS];
  __shared__ float sc[NWIN];
  __shared__ int   flag;

  // ---- streaming phase: 4 slices (32 channels each) per block ----
  const int sl = blockIdx.y * 4 + wave;
  if (lane < NQ) {
    const float4* p = x + ((size_t)b * NCH + (size_t)sl * CPS) * NQ + lane;
    float ax = 0.f, ay = 0.f, az = 0.f, aw = 0.f;
#pragma unroll 8
    for (int c = 0; c < CPS; ++c) {
      float4 v = p[(size_t)c * NQ];
      ax += v.x; ay += v.y; az += v.z; aw += v.w;
    }
    float4 o; o.x = ax; o.y = ay; o.z = az; o.w = aw;
    part[((size_t)b * NSL + sl) * NQ + lane] = o;
  }
  __syncthreads();                      // all waves' stores drained (vmcnt0 before barrier)
  if (tid == 0) {
    __threadfence();                    // release: partials device-visible
    flag = (atomicAdd(&cnt[b], 1) == BPB - 1);
  }
  __syncthreads();
  if (!flag) return;

  // ---- this is the last block for batch b: reduce + windows + NMS ----
  __threadfence();                      // acquire: invalidate stale cached lines

  if (tid < NPOS) {
    float acc = 0.f;
    const float* p = (const float*)part + (size_t)b * NSL * NPOS + tid;
#pragma unroll 8
    for (int slc = 0; slc < NSL; ++slc) acc += p[slc * NPOS];
    s[tid] = acc;
  }
  __syncthreads();

  for (int w = tid; w < NWIN; w += 256) {
    int r = 0;
    while (w >= g_wbase[r + 1]) ++r;
    const int l  = w - g_wbase[r];
    const int RH = g_rh[r], RW = g_rw[r];
    const int ww = SZ - RW + 1;
    const int xi = l / ww, yi = l % ww;
    float sum = 0.f;
    for (int i = 0; i < RH; ++i)
      for (int j = 0; j < RW; ++j)
        sum += s[(xi + i) * SZ + (yi + j)];
    const float score = sum / (float)(RH * RW);
    sc[w] = score;
    out[NB * PN * 2 + b * NWIN + w] = score;
  }
  __syncthreads();

  if (wave < 3) {
    const int glo[3] = {0, 361, 602};
    const int ghi[3] = {361, 602, 917};
    const int gns[3] = {2, 3, 2};
    const int gob[3] = {0, 2, 5};
    const int lo = glo[wave], hi = ghi[wave];
    const int nsel = gns[wave], obase = gob[wave];

    float wk[KPER], X1[KPER], Y1[KPER], X2[KPER], Y2[KPER], AR[KPER];
#pragma unroll
    for (int k = 0; k < KPER; ++k) {
      const int j = lo + lane + k * 64;
      const bool v = j < hi;
      const int jj = v ? j : lo;
      wk[k] = v ? sc[jj] : -INFINITY;
      decode_box(jj, X1[k], Y1[k], X2[k], Y2[k], AR[k]);
    }

    for (int st = 0; st < nsel; ++st) {
      float bv = -INFINITY; int bj = 0x7fffffff;
#pragma unroll
      for (int k = 0; k < KPER; ++k) {
        const int j = lo + lane + k * 64;
        if (wk[k] > bv) { bv = wk[k]; bj = j; }   // strict > keeps smallest j
      }
      for (int off = 32; off > 0; off >>= 1) {
        const float ov = __shfl_xor(bv, off);
        const int   oj = __shfl_xor(bj, off);
        if (ov > bv || (ov == bv && oj < bj)) { bv = ov; bj = oj; }
      }
      // bj uniform; recompute its box scalar-wise
      float sx1, sy1, sx2, sy2, sar;
      decode_box(bj, sx1, sy1, sx2, sy2, sar);
      if (lane == 0) {
        out[b * PN + obase + st]           = (float)bj;
        out[NB * PN + b * PN + obase + st] = sc[bj];
      }
#pragma unroll
      for (int k = 0; k < KPER; ++k) {
        const int j = lo + lane + k * 64;
        const float ix1 = fmaxf(X1[k], sx1);
        const float iy1 = fmaxf(Y1[k], sy1);
        const float ix2 = fminf(X2[k], sx2);
        const float iy2 = fminf(Y2[k], sy2);
        const float lw = ix2 - ix1 + 1.f;
        const float lh = iy2 - iy1 + 1.f;
        const float inter = (lw < 0.f || lh < 0.f) ? 0.f : lw * lh;
        const float iou = inter / (AR[k] + sar - inter);
        if (iou > 0.25f || j == bj) wk[k] = -INFINITY;
      }
    }
  }
}

extern "C" void kernel_launch(void* const* d_in, const int* in_sizes, int n_in,
                              void* d_out, int out_size, void* d_ws, size_t ws_size,
                              hipStream_t stream) {
  const float4* x = (const float4*)d_in[0];
  float* out = (float*)d_out;
  float4* part = (float4*)d_ws;
  int* cnt = (int*)((char*)d_ws + PART_BYTES);

  hipMemsetAsync(cnt, 0, NB * sizeof(int), stream);
  dim3 g1(NB, NSL / 4);
  k_fused<<<g1, 256, 0, stream>>>(x, part, cnt, out);
}

// Round 4
// 40.778 us; speedup vs baseline: 2.0941x; 2.0941x over previous
//
#include <hip/hip_runtime.h>
#include <math.h>

// ---- problem constants ----
#define NCH   2048
#define SZ    14
#define NPOS  (SZ*SZ)        // 196
#define NQ    (NPOS/4)       // 49 float4 per channel plane
#define BLK_CH 64            // channels per k1 block
#define SPB   (NCH/BLK_CH)   // 32 slices (blocks) per batch
#define TACT  245            // 5*49 active threads in k1
#define NWIN  917
#define NB    64
#define PN    7
#define KPER  6              // ceil(361/64) strided candidates per lane

// window tables (13 ratios)
__device__ const int g_rh[13]    = {4,3,5,6,5,7,8,6,10,7,9,7,10};
__device__ const int g_rw[13]    = {4,5,3,6,7,5,8,10,6,9,7,10,7};
__device__ const int g_wbase[14] = {0,121,241,361,442,522,602,651,696,741,789,837,877,917};

// -------- kernel 1: dense coalesced channel-sum --------
// Block (b, blk) reads the contiguous float4 range of 64 channels:
// [ (b*2048+blk*64)*49 , +3136 ). Thread t<245 reads f = base + i*245 + t;
// since 245 % 49 == 0, each thread's position p4 = t % 49 is constant ->
// register accumulation, perfectly dense loads.
__global__ __launch_bounds__(256) void k_chansum(const float4* __restrict__ x,
                                                 float4* __restrict__ part) {
  const int b   = blockIdx.x;
  const int blk = blockIdx.y;
  const int t   = threadIdx.x;

  __shared__ float4 red[5][49];

  if (t < TACT) {
    const size_t base = ((size_t)b * NCH + (size_t)blk * BLK_CH) * NQ;
    float ax = 0.f, ay = 0.f, az = 0.f, aw = 0.f;
#pragma unroll
    for (int i = 0; i < 12; ++i) {
      const float4 v = x[base + i * TACT + t];
      ax += v.x; ay += v.y; az += v.z; aw += v.w;
    }
    if (t < 196) {                       // tail: 12*245=2940, 3136-2940=196
      const float4 v = x[base + 2940 + t];
      ax += v.x; ay += v.y; az += v.z; aw += v.w;
    }
    float4 o; o.x = ax; o.y = ay; o.z = az; o.w = aw;
    red[t / 49][t % 49] = o;
  }
  __syncthreads();

  if (t < 49) {
    const float4 r0 = red[0][t], r1 = red[1][t], r2 = red[2][t],
                 r3 = red[3][t], r4 = red[4][t];
    float4 o;
    o.x = r0.x + r1.x + r2.x + r3.x + r4.x;
    o.y = r0.y + r1.y + r2.y + r3.y + r4.y;
    o.z = r0.z + r1.z + r2.z + r3.z + r4.z;
    o.w = r0.w + r1.w + r2.w + r3.w + r4.w;
    part[((size_t)b * SPB + blk) * NQ + t] = o;
  }
}

// -------- kernel 2: windows + wave-parallel NMS, one block per batch --------
__global__ __launch_bounds__(256) void k_nms(const float* __restrict__ part,
                                             float* __restrict__ out) {
  const int b    = blockIdx.x;
  const int tid  = threadIdx.x;
  const int lane = tid & 63;
  const int wave = tid >> 6;

  __shared__ float s[NPOS];
  __shared__ float sc[NWIN];
  __shared__ float bx1[NWIN], by1[NWIN], bx2[NWIN], by2[NWIN], bar[NWIN];

  // reduce 32 block-partials -> s[196]
  if (tid < NPOS) {
    float acc = 0.f;
    const float* p = part + (size_t)b * SPB * NPOS + tid;
#pragma unroll 8
    for (int sl = 0; sl < SPB; ++sl) acc += p[sl * NPOS];
    s[tid] = acc;
  }
  __syncthreads();

  // window scores + coords (clamp AFTER x2/y2, exactly as reference)
  for (int w = tid; w < NWIN; w += 256) {
    int r = 0;
    while (w >= g_wbase[r + 1]) ++r;
    const int l  = w - g_wbase[r];
    const int RH = g_rh[r], RW = g_rw[r];
    const int ww = SZ - RW + 1;
    const int xi = l / ww, yi = l % ww;
    float sum = 0.f;
    for (int i = 0; i < RH; ++i)
      for (int j = 0; j < RW; ++j)
        sum += s[(xi + i) * SZ + (yi + j)];
    const float score = sum / (float)(RH * RW);
    sc[w] = score;
    out[NB * PN * 2 + b * NWIN + w] = score;
    float x1 = (float)(xi * 32 - 1);
    float y1 = (float)(yi * 32 - 1);
    float x2 = x1 + (float)(RH * 32);
    float y2 = y1 + (float)(RW * 32);
    if (x1 < 0.f) x1 = 0.f;
    if (y1 < 0.f) y1 = 0.f;
    bx1[w] = x1; by1[w] = y1; bx2[w] = x2; by2[w] = y2;
    bar[w] = (x2 - x1 + 1.f) * (y2 - y1 + 1.f);
  }
  __syncthreads();

  // one wave per NMS group, wave-synchronous (no barriers)
  if (wave < 3) {
    const int glo[3] = {0, 361, 602};
    const int ghi[3] = {361, 602, 917};
    const int gns[3] = {2, 3, 2};
    const int gob[3] = {0, 2, 5};
    const int lo = glo[wave], hi = ghi[wave];
    const int nsel = gns[wave], obase = gob[wave];

    float wk[KPER], X1[KPER], Y1[KPER], X2[KPER], Y2[KPER], AR[KPER];
#pragma unroll
    for (int k = 0; k < KPER; ++k) {
      const int j = lo + lane + k * 64;
      const bool v = j < hi;
      const int jj = v ? j : lo;
      wk[k] = v ? sc[jj] : -INFINITY;
      X1[k] = bx1[jj]; Y1[k] = by1[jj];
      X2[k] = bx2[jj]; Y2[k] = by2[jj]; AR[k] = bar[jj];
    }

    for (int st = 0; st < nsel; ++st) {
      float bv = -INFINITY; int bj = 0x7fffffff;
#pragma unroll
      for (int k = 0; k < KPER; ++k) {
        const int j = lo + lane + k * 64;
        if (wk[k] > bv) { bv = wk[k]; bj = j; }   // strict > keeps smallest j
      }
      for (int off = 32; off > 0; off >>= 1) {
        const float ov = __shfl_xor(bv, off);
        const int   oj = __shfl_xor(bj, off);
        if (ov > bv || (ov == bv && oj < bj)) { bv = ov; bj = oj; }
      }
      const float sx1 = bx1[bj], sy1 = by1[bj];
      const float sx2 = bx2[bj], sy2 = by2[bj], sar = bar[bj];
      if (lane == 0) {
        out[b * PN + obase + st]           = (float)bj;
        out[NB * PN + b * PN + obase + st] = sc[bj];
      }
#pragma unroll
      for (int k = 0; k < KPER; ++k) {
        const int j = lo + lane + k * 64;
        const float ix1 = fmaxf(X1[k], sx1);
        const float iy1 = fmaxf(Y1[k], sy1);
        const float ix2 = fminf(X2[k], sx2);
        const float iy2 = fminf(Y2[k], sy2);
        const float lw = ix2 - ix1 + 1.f;
        const float lh = iy2 - iy1 + 1.f;
        const float inter = (lw < 0.f || lh < 0.f) ? 0.f : lw * lh;
        const float iou = inter / (AR[k] + sar - inter);
        if (iou > 0.25f || j == bj) wk[k] = -INFINITY;
      }
    }
  }
}

extern "C" void kernel_launch(void* const* d_in, const int* in_sizes, int n_in,
                              void* d_out, int out_size, void* d_ws, size_t ws_size,
                              hipStream_t stream) {
  const float4* x = (const float4*)d_in[0];
  float* out = (float*)d_out;
  float4* part = (float4*)d_ws;   // 64*32*49 float4 = 1.6 MB

  dim3 g1(NB, SPB);
  k_chansum<<<g1, 256, 0, stream>>>(x, part);
  k_nms<<<NB, 256, 0, stream>>>((const float*)d_ws, out);
}